// Round 2
// 699.186 us; speedup vs baseline: 1.0640x; 1.0640x over previous
//
#include <hip/hip_runtime.h>
#include <hip/hip_bf16.h>
#include <math.h>

// RecurrentFFN: B=1024, D=1024, H=4096, C=5120.
// FAST PATH (ws >= 114MiB): pre-convert fp32 weights/activations once into
// bf16 "tile images" = the exact 16KB LDS image per (128-col x 64-k) tile,
// layout: tile[(kc*128 + j)*8 + kr] = bf16(Mat[k0+kc*8+kr][n0+j]) (B) or
//         bf16(Act[m0+j][k0+kc*8+kr]) (A).
// GEMMs then stage via global_load_lds dwordx4 (zero staging VALU), m97
// structure: stage -> sync -> ds_read_b128 + MFMA -> sync.
// Producers fuse image writes: gemm1 epilogue writes r*h tile-image (gemm2 A),
// ln_h writes new_h tile-image (gemm3 A). Numerics identical to old path.
// FALLBACK (small ws): previous verified kernel (in-GEMM conversion).

typedef unsigned short u16;
typedef unsigned int u32;
typedef __attribute__((ext_vector_type(8))) short short8;
typedef __attribute__((ext_vector_type(4))) float floatx4;

#define B_ROWS 1024
#define H_DIM 4096
#define D_DIM 1024
#define LDA_S 72   // padded As row stride (u16) for fallback kernel

__device__ __forceinline__ float bf2f(u16 v) {
  u32 u = ((u32)v) << 16;
  return __builtin_bit_cast(float, u);
}
__device__ __forceinline__ u16 f2bf(float f) {
  u32 u = __builtin_bit_cast(u32, f);
  u32 r = (u + 0x7fffu + ((u >> 16) & 1u)) >> 16;   // round-to-nearest-even
  return (u16)r;
}
__device__ __forceinline__ u32 pkbf(float lo, float hi) {
  return (u32)f2bf(lo) | ((u32)f2bf(hi) << 16);
}

// global -> LDS direct copy, 16B per lane. LDS dest = wave-uniform base +
// lane*16 (linear); global source is per-lane. Direct addrspacecast form
// (compiler inserts proper generic->AS1/AS3 conversion).
__device__ __forceinline__ void gload_lds16(const u16* g, u16* l) {
  __builtin_amdgcn_global_load_lds(
      (const __attribute__((address_space(1))) void*)g,
      (__attribute__((address_space(3))) void*)l, 16, 0, 0);
}

// ---------------- conversion kernels (fast path) ----------------

// Weights W (fp32 [K,N] row-major) -> tile images [nb][kt] (16KB each).
// Optional second matrix W1 appended in nb (nb >= nbHalf).
__launch_bounds__(256)
__global__ void conv_w_k(const float* __restrict__ W0, const float* __restrict__ W1,
                         u16* __restrict__ img, int ldb, int KT, int nbHalf) {
  const int nb = blockIdx.x;
  const int kt = blockIdx.y;
  const float* W = (nb < nbHalf) ? W0 : W1;
  const int nbl = (nb < nbHalf) ? nb : (nb - nbHalf);
  const float* src = W + (size_t)kt * 64 * ldb + (size_t)nbl * 128;
  u16* dst = img + ((size_t)nb * KT + kt) * 8192;
  const int t = threadIdx.x;
  const int n = t & 127;
  const int half = t >> 7;
#pragma unroll
  for (int pass = 0; pass < 4; ++pass) {
    const int kc = half * 4 + pass;
    const float* sp = src + (size_t)(kc * 8) * ldb + n;
    uint4 o;
    o.x = pkbf(sp[0],                 sp[(size_t)ldb]);
    o.y = pkbf(sp[(size_t)2 * ldb],   sp[(size_t)3 * ldb]);
    o.z = pkbf(sp[(size_t)4 * ldb],   sp[(size_t)5 * ldb]);
    o.w = pkbf(sp[(size_t)6 * ldb],   sp[(size_t)7 * ldb]);
    *(uint4*)(dst + (size_t)(kc * 128 + n) * 8) = o;
  }
}

// Activations x [1024,1024] and h [1024,4096] -> tile images [mb][kt].
// grid (80, 8): kt<16 -> x, else h.
__launch_bounds__(256)
__global__ void conv_xh_k(const float* __restrict__ x, const float* __restrict__ h,
                          u16* __restrict__ imgX, u16* __restrict__ imgH) {
  const int kt = blockIdx.x;
  const int mb = blockIdx.y;
  const float* src;
  u16* dst;
  int lda;
  if (kt < 16) {
    lda = 1024;
    src = x + (size_t)mb * 128 * lda + (size_t)kt * 64;
    dst = imgX + ((size_t)mb * 16 + kt) * 8192;
  } else {
    lda = 4096;
    src = h + (size_t)mb * 128 * lda + (size_t)(kt - 16) * 64;
    dst = imgH + ((size_t)mb * 64 + (kt - 16)) * 8192;
  }
  const int t = threadIdx.x;
  const int j = t & 127;
  const int half = t >> 7;
  const float* sp = src + (size_t)j * lda + half * 32;
#pragma unroll
  for (int pass = 0; pass < 4; ++pass) {
    const int kc = half * 4 + pass;
    const float4 a = *(const float4*)(sp + pass * 8);
    const float4 b = *(const float4*)(sp + pass * 8 + 4);
    uint4 o;
    o.x = pkbf(a.x, a.y);
    o.y = pkbf(a.z, a.w);
    o.z = pkbf(b.x, b.y);
    o.w = pkbf(b.z, b.w);
    *(uint4*)(dst + (size_t)(kc * 128 + j) * 8) = o;
  }
}

// ---------------- image GEMM (fast path) ----------------
// MODE 1: B=[Wu|Wr] imgs; first half -> u=sigmoid fp32 (outF linear);
//         second half -> rh=sigmoid*h bf16 written to imgRH tile layout (outB0).
// MODE 2: B=[Wg|Wup]; first -> g bf16 linear (outB0), second -> up (outB1).
// MODE 3: B=Wd img; outF = acc + bias fp32 linear.
template <int MODE>
__launch_bounds__(256)
__global__ void gemm_img(const u16* __restrict__ A0, const u16* __restrict__ A1,
                         const u16* __restrict__ Bimg,
                         const float* __restrict__ bias0, const float* __restrict__ bias1,
                         const float* __restrict__ hglob,
                         float* __restrict__ outF, u16* __restrict__ outB0,
                         u16* __restrict__ outB1) {
  constexpr int KT = (MODE == 3) ? 64 : 80;
  constexpr int KSPLIT = (MODE == 3) ? 64 : 16;   // tiles from A0 (x), rest from A1
  constexpr int A1T = KT - KSPLIT;

  const int bx = blockIdx.x;
  const int by = blockIdx.y;
  const int n0 = bx * 128;
  const int m0 = by * 128;
  const bool second = (MODE != 3) && (n0 >= 4096);
  const int ncol0 = second ? (n0 - 4096) : n0;

  __shared__ __align__(16) u16 As[8192];
  __shared__ __align__(16) u16 Bs[8192];

  const int t = threadIdx.x;
  const int w = t >> 6;
  const int lane = t & 63;
  const int q = lane >> 4;
  const int i16 = lane & 15;
  const int wm = (w >> 1) * 64;
  const int wn = (w & 1) * 64;

  floatx4 acc[4][4] = {};

  const u16* at = A0 + (size_t)by * KSPLIT * 8192;
  const u16* at1 = A1 + (size_t)by * A1T * 8192;
  const u16* btk = Bimg + (size_t)bx * KT * 8192;

  for (int kt = 0; kt < KT; ++kt) {
    // ---- stage: 16KB A + 16KB B via global_load_lds (4+4 per wave) ----
#pragma unroll
    for (int i = 0; i < 4; ++i) {
      const int ch = (i * 4 + w) * 512;   // u16 offset of a 1KB chunk
      gload_lds16(at + ch + lane * 8, &As[ch]);
      gload_lds16(btk + ch + lane * 8, &Bs[ch]);
    }
    __syncthreads();
    // ---- MFMA: 2 k-steps of 32, 4x4 tiles of 16x16 per wave ----
#pragma unroll
    for (int s = 0; s < 2; ++s) {
      const int c = s * 4 + q;
      short8 av[4], bv[4];
#pragma unroll
      for (int tm = 0; tm < 4; ++tm)
        av[tm] = *(const short8*)(&As[(size_t)(c * 128 + wm + tm * 16 + i16) * 8]);
#pragma unroll
      for (int tn = 0; tn < 4; ++tn)
        bv[tn] = *(const short8*)(&Bs[(size_t)(c * 128 + wn + tn * 16 + i16) * 8]);
#pragma unroll
      for (int tm = 0; tm < 4; ++tm)
#pragma unroll
        for (int tn = 0; tn < 4; ++tn)
          acc[tm][tn] = __builtin_amdgcn_mfma_f32_16x16x32_bf16(av[tm], bv[tn], acc[tm][tn], 0, 0, 0);
    }
    __syncthreads();
    at = (kt == KSPLIT - 1) ? at1 : (at + 8192);
    btk += 8192;
  }

  // ---- epilogue ----
  const float* __restrict__ biasP = second ? bias1 : bias0;
#pragma unroll
  for (int tm = 0; tm < 4; ++tm) {
#pragma unroll
    for (int tn = 0; tn < 4; ++tn) {
      const int nloc = ncol0 + wn + tn * 16 + i16;
      const float b = biasP[nloc];
      const int mbase = m0 + wm + tm * 16 + q * 4;
#pragma unroll
      for (int r = 0; r < 4; ++r) {
        const int m = mbase + r;
        const float v = acc[tm][tn][r] + b;
        if (MODE == 1) {
          const float sg = 1.f / (1.f + __expf(-v));
          if (!second) {
            outF[(size_t)m * 4096 + nloc] = sg;                  // u gate fp32
          } else {
            const float rh = sg * hglob[(size_t)m * 4096 + nloc];
            // write r*h into gemm2's A tile image (k = 1024 + nloc)
            const size_t tb = ((size_t)(m >> 7) * 64 + (nloc >> 6)) * 8192;
            outB0[tb + (size_t)((((nloc >> 3) & 7) * 128) + (m & 127)) * 8 + (nloc & 7)] = f2bf(rh);
          }
        } else if (MODE == 2) {
          if (!second) outB0[(size_t)m * 4096 + nloc] = f2bf(v);  // g pre-act
          else         outB1[(size_t)m * 4096 + nloc] = f2bf(v);  // up pre-act
        } else {
          outF[(size_t)m * 1024 + nloc] = v;                      // down-proj pre-act
        }
      }
    }
  }
}

// ---------------- fallback GEMM (previous verified kernel) ----------------
template <int MODE>
__launch_bounds__(256)
__global__ void gemm_k(const float* __restrict__ Af0, const float* __restrict__ Af1,
                       const u16* __restrict__ Ab,
                       const float* __restrict__ Bg0, const float* __restrict__ Bg1,
                       const float* __restrict__ bias0, const float* __restrict__ bias1,
                       const float* __restrict__ hglob,
                       float* __restrict__ outF, u16* __restrict__ outB0,
                       u16* __restrict__ outB1) {
  constexpr int K_TOT = (MODE == 3) ? 4096 : 5120;
  constexpr int KT = K_TOT / 64;
  constexpr int LDB = (MODE == 3) ? 1024 : 4096;

  const int n0 = blockIdx.x * 128;
  const int m0 = blockIdx.y * 128;
  const bool second = (MODE != 3) && (n0 >= 4096);
  const float* __restrict__ Bg = second ? Bg1 : Bg0;
  const int ncol0 = second ? (n0 - 4096) : n0;

  __shared__ __align__(16) u16 As[128 * LDA_S];
  __shared__ __align__(16) u16 Bs[64 * 128];

  const int t = threadIdx.x;
  const int w = t >> 6;
  const int lane = t & 63;
  const int q = lane >> 4;
  const int i16 = lane & 15;
  const int wm = (w >> 1) * 64;
  const int wn = (w & 1) * 64;

  floatx4 acc[4][4] = {};

  for (int kt = 0; kt < KT; ++kt) {
    const int k0 = kt * 64;
    const bool a_is_bf16 = (MODE == 2) && (k0 >= 1024);
    if (a_is_bf16) {
      const u16* Ag = Ab;
      const int lda = 4096;
      const int krel = k0 - 1024;
#pragma unroll
      for (int c = 0; c < 4; ++c) {
        const int p = c * 256 + t;
        const int row = p >> 3;
        const int cp = p & 7;
        const uint4 v = *(const uint4*)(Ag + (size_t)(m0 + row) * lda + krel + cp * 8);
        *(uint4*)(&As[row * LDA_S + cp * 8]) = v;
      }
    } else {
      const float* Ag;
      int lda, krel;
      if (MODE == 3)      { Ag = Af0; lda = 4096; krel = k0; }
      else if (k0 < 1024) { Ag = Af0; lda = 1024; krel = k0; }
      else                { Ag = Af1; lda = 4096; krel = k0 - 1024; }
#pragma unroll
      for (int c = 0; c < 8; ++c) {
        const int p = c * 256 + t;
        const int row = p >> 4;
        const int cp = p & 15;
        const float4 v = *(const float4*)(Ag + (size_t)(m0 + row) * lda + krel + cp * 4);
        ushort4 o;
        o.x = f2bf(v.x); o.y = f2bf(v.y); o.z = f2bf(v.z); o.w = f2bf(v.w);
        *(ushort4*)(&As[row * LDA_S + cp * 4]) = o;
      }
    }
#pragma unroll
    for (int cc = 0; cc < 2; ++cc) {
      const int c = 2 * w + cc;
      const float* bp = Bg + (size_t)(k0 + c * 8) * LDB + ncol0;
#pragma unroll
      for (int hn = 0; hn < 2; ++hn) {
        const int n = lane + hn * 64;
        const float* src = bp + n;
        u32 p0 = (u32)f2bf(src[0 * LDB]) | ((u32)f2bf(src[1 * LDB]) << 16);
        u32 p1 = (u32)f2bf(src[2 * LDB]) | ((u32)f2bf(src[3 * LDB]) << 16);
        u32 p2 = (u32)f2bf(src[4 * LDB]) | ((u32)f2bf(src[5 * LDB]) << 16);
        u32 p3 = (u32)f2bf(src[6 * LDB]) | ((u32)f2bf(src[7 * LDB]) << 16);
        *(uint4*)(&Bs[(size_t)(c * 128 + n) * 8]) = make_uint4(p0, p1, p2, p3);
      }
    }
    __syncthreads();
#pragma unroll
    for (int s = 0; s < 2; ++s) {
      short8 av[4], bv[4];
#pragma unroll
      for (int tm = 0; tm < 4; ++tm) {
        const int r = wm + tm * 16 + i16;
        av[tm] = *(const short8*)(&As[r * LDA_S + (s * 4 + q) * 8]);
      }
#pragma unroll
      for (int tn = 0; tn < 4; ++tn) {
        const int n = wn + tn * 16 + i16;
        const int c = s * 4 + q;
        bv[tn] = *(const short8*)(&Bs[(size_t)(c * 128 + n) * 8]);
      }
#pragma unroll
      for (int tm = 0; tm < 4; ++tm)
#pragma unroll
        for (int tn = 0; tn < 4; ++tn)
          acc[tm][tn] = __builtin_amdgcn_mfma_f32_16x16x32_bf16(av[tm], bv[tn], acc[tm][tn], 0, 0, 0);
    }
    __syncthreads();
  }

  const float* __restrict__ biasP = second ? bias1 : bias0;
  constexpr int LDO = (MODE == 3) ? 1024 : 4096;
#pragma unroll
  for (int tm = 0; tm < 4; ++tm) {
#pragma unroll
    for (int tn = 0; tn < 4; ++tn) {
      const int nloc = ncol0 + wn + tn * 16 + i16;
      const float b = biasP[nloc];
      const int mbase = m0 + wm + tm * 16 + q * 4;
#pragma unroll
      for (int r = 0; r < 4; ++r) {
        const int m = mbase + r;
        const float v = acc[tm][tn][r] + b;
        const size_t oidx = (size_t)m * LDO + nloc;
        if (MODE == 1) {
          const float sg = 1.f / (1.f + __expf(-v));
          if (!second) outF[oidx] = sg;
          else         outB0[oidx] = f2bf(sg * hglob[oidx]);
        } else if (MODE == 2) {
          if (!second) outB0[oidx] = f2bf(v);
          else         outB1[oidx] = f2bf(v);
        } else {
          outF[oidx] = v;
        }
      }
    }
  }
}

// ---------------- LayerNorms ----------------
// u_f (fp32) ALIASES out (in-place, same offsets): reads precede barrier,
// writes after; one block owns one row. imgNH (may be null): new_h bf16
// tile-image for gemm3's A.
__launch_bounds__(256)
__global__ void ln_h_k(const float* u_f, const u16* __restrict__ wsg,
                       const u16* __restrict__ wsup, const float* __restrict__ h,
                       const float* __restrict__ gamma, const float* __restrict__ beta,
                       float* out, u16* __restrict__ imgNH) {
  const int row = blockIdx.x, t = threadIdx.x;
  const size_t base = (size_t)row * H_DIM;
  const int i0 = t * 16;
  float tv[16];
  float s = 0.f, s2 = 0.f;
#pragma unroll
  for (int j = 0; j < 16; ++j) {
    const int idx = i0 + j;
    const float u = u_f[base + idx];
    const float g = bf2f(wsg[base + idx]);
    const float up = bf2f(wsup[base + idx]);
    const float hh = h[base + idx];
    const float sw = (g / (1.f + __expf(-g))) * up;   // silu(g)*up
    const float x = (2.f - u) * hh + u * sw;
    tv[j] = x; s += x; s2 += x * x;
  }
#pragma unroll
  for (int off = 32; off; off >>= 1) {
    s += __shfl_down(s, off);
    s2 += __shfl_down(s2, off);
  }
  __shared__ float red[8];
  const int w = t >> 6, lane = t & 63;
  if (lane == 0) { red[w] = s; red[4 + w] = s2; }
  __syncthreads();
  const float S = red[0] + red[1] + red[2] + red[3];
  const float S2 = red[4] + red[5] + red[6] + red[7];
  const float mean = S * (1.f / (float)H_DIM);
  const float var = fmaxf(S2 * (1.f / (float)H_DIM) - mean * mean, 0.f);
  const float rstd = rsqrtf(var + 1e-3f);
#pragma unroll
  for (int cc = 0; cc < 2; ++cc) {
    float o[8];
#pragma unroll
    for (int jj = 0; jj < 8; ++jj) {
      const int idx = i0 + cc * 8 + jj;
      o[jj] = (tv[cc * 8 + jj] - mean) * rstd * gamma[idx] + beta[idx];
      out[base + idx] = o[jj];
    }
    if (imgNH) {
      const int idx8 = i0 + cc * 8;
      uint4 v;
      v.x = pkbf(o[0], o[1]);
      v.y = pkbf(o[2], o[3]);
      v.z = pkbf(o[4], o[5]);
      v.w = pkbf(o[6], o[7]);
      *(uint4*)(&imgNH[((size_t)(row >> 7) * 64 + (idx8 >> 6)) * 8192 +
                       (size_t)((((idx8 >> 3) & 7) * 128) + (row & 127)) * 8]) = v;
    }
  }
}

__launch_bounds__(256)
__global__ void ln_o_k(float* io, const float* __restrict__ gamma,
                       const float* __restrict__ beta) {
  const int row = blockIdx.x, t = threadIdx.x;
  const size_t base = (size_t)row * D_DIM;
  const int i0 = t * 4;
  float tv[4];
  float s = 0.f, s2 = 0.f;
#pragma unroll
  for (int j = 0; j < 4; ++j) {
    const float x = io[base + i0 + j];
    tv[j] = x; s += x; s2 += x * x;
  }
#pragma unroll
  for (int off = 32; off; off >>= 1) {
    s += __shfl_down(s, off);
    s2 += __shfl_down(s2, off);
  }
  __shared__ float red[8];
  const int w = t >> 6, lane = t & 63;
  if (lane == 0) { red[w] = s; red[4 + w] = s2; }
  __syncthreads();
  const float S = red[0] + red[1] + red[2] + red[3];
  const float S2 = red[4] + red[5] + red[6] + red[7];
  const float mean = S * (1.f / (float)D_DIM);
  const float var = fmaxf(S2 * (1.f / (float)D_DIM) - mean * mean, 0.f);
  const float rstd = rsqrtf(var + 1e-3f);
#pragma unroll
  for (int j = 0; j < 4; ++j) {
    const int idx = i0 + j;
    io[base + idx] = (tv[j] - mean) * rstd * gamma[idx] + beta[idx];
  }
}

extern "C" void kernel_launch(void* const* d_in, const int* in_sizes, int n_in,
                              void* d_out, int out_size, void* d_ws, size_t ws_size,
                              hipStream_t stream) {
  (void)in_sizes; (void)n_in; (void)out_size;
  const float* x       = (const float*)d_in[0];
  const float* h       = (const float*)d_in[1];
  const float* W_u     = (const float*)d_in[2];
  const float* b_u     = (const float*)d_in[3];
  const float* W_r     = (const float*)d_in[4];
  const float* b_r     = (const float*)d_in[5];
  const float* W_g     = (const float*)d_in[6];
  const float* b_g     = (const float*)d_in[7];
  const float* W_up    = (const float*)d_in[8];
  const float* b_up    = (const float*)d_in[9];
  const float* W_d     = (const float*)d_in[10];
  const float* b_d     = (const float*)d_in[11];
  const float* gamma_h = (const float*)d_in[12];
  const float* beta_h  = (const float*)d_in[13];
  const float* gamma_o = (const float*)d_in[14];
  const float* beta_o  = (const float*)d_in[15];

  float* out_final = (float*)d_out;                              // [B,D] fp32
  float* out_newh  = (float*)d_out + (size_t)B_ROWS * D_DIM;     // [B,H] fp32
  float* u_buf = out_newh;   // u gate fp32 parked in d_out newh region
  float* o_pre = out_final;  // GEMM3 pre-act fp32 in d_out out region

  dim3 blk(256);

  // ---- fast-path workspace layout (bytes) ----
  const size_t SZ_W  = (size_t)64 * 80 * 16384;   // 80 MiB: [Wu|Wr] / [Wg|Wup] / Wd imgs
  const size_t SZ_X  = (size_t)8 * 16 * 16384;    //  2 MiB
  const size_t SZ_H  = (size_t)8 * 64 * 16384;    //  8 MiB (also reused as imgNH)
  const size_t SZ_RH = SZ_H;
  const size_t SZ_G  = (size_t)B_ROWS * H_DIM * 2;
  const size_t SZ_UP = SZ_G;
  const size_t NEED  = SZ_W + SZ_X + SZ_H + SZ_RH + SZ_G + SZ_UP;  // 114 MiB

  if (ws_size >= NEED) {
    char* ws = (char*)d_ws;
    u16* imgW  = (u16*)(ws);
    u16* imgX  = (u16*)(ws + SZ_W);
    u16* imgH  = (u16*)(ws + SZ_W + SZ_X);
    u16* imgNH = imgH;                             // imgH dead after gemm1
    u16* imgRH = (u16*)(ws + SZ_W + SZ_X + SZ_H);
    u16* ws_g  = (u16*)(ws + SZ_W + SZ_X + SZ_H + SZ_RH);
    u16* ws_up = (u16*)(ws + SZ_W + SZ_X + SZ_H + SZ_RH + SZ_G);

    conv_xh_k<<<dim3(80, 8), blk, 0, stream>>>(x, h, imgX, imgH);
    conv_w_k<<<dim3(64, 80), blk, 0, stream>>>(W_u, W_r, imgW, 4096, 80, 32);
    gemm_img<1><<<dim3(64, 8), blk, 0, stream>>>(imgX, imgH, imgW, b_u, b_r, h,
                                                 u_buf, imgRH, nullptr);
    conv_w_k<<<dim3(64, 80), blk, 0, stream>>>(W_g, W_up, imgW, 4096, 80, 32);
    gemm_img<2><<<dim3(64, 8), blk, 0, stream>>>(imgX, imgRH, imgW, b_g, b_up, nullptr,
                                                 nullptr, ws_g, ws_up);
    ln_h_k<<<dim3(B_ROWS), blk, 0, stream>>>(u_buf, ws_g, ws_up, h, gamma_h, beta_h,
                                             out_newh, imgNH);
    conv_w_k<<<dim3(8, 64), blk, 0, stream>>>(W_d, nullptr, imgW, 1024, 64, 8);
    gemm_img<3><<<dim3(8, 8), blk, 0, stream>>>(imgNH, imgNH, imgW, b_d, nullptr, nullptr,
                                                o_pre, nullptr, nullptr);
    ln_o_k<<<dim3(B_ROWS), blk, 0, stream>>>(o_pre, gamma_o, beta_o);
  } else {
    // fallback: previous verified path (24 MB workspace)
    char* ws = (char*)d_ws;
    u16* ws_rh = (u16*)(ws);
    u16* ws_g  = (u16*)(ws + (size_t)8 * 1024 * 1024);
    u16* ws_up = (u16*)(ws + (size_t)16 * 1024 * 1024);

    gemm_k<1><<<dim3(64, 8), blk, 0, stream>>>(x, h, nullptr, W_u, W_r, b_u, b_r, h,
                                               u_buf, ws_rh, nullptr);
    gemm_k<2><<<dim3(64, 8), blk, 0, stream>>>(x, nullptr, ws_rh, W_g, W_up, b_g, b_up,
                                               nullptr, nullptr, ws_g, ws_up);
    ln_h_k<<<dim3(B_ROWS), blk, 0, stream>>>(u_buf, ws_g, ws_up, h, gamma_h, beta_h,
                                             out_newh, nullptr);
    gemm_k<3><<<dim3(8, 8), blk, 0, stream>>>(out_newh, nullptr, nullptr, W_d, nullptr,
                                              b_d, nullptr, nullptr, o_pre, nullptr, nullptr);
    ln_o_k<<<dim3(B_ROWS), blk, 0, stream>>>(o_pre, gamma_o, beta_o);
  }
}

// Round 3
// 643.479 us; speedup vs baseline: 1.1562x; 1.0866x over previous
//
#include <hip/hip_runtime.h>
#include <hip/hip_bf16.h>
#include <math.h>

// RecurrentFFN: B=1024, D=1024, H=4096, C=5120.
// FAST PATH (ws >= 114MiB): pre-converted bf16 tile images (16KB = exact LDS
// image per 128x64 tile). GEMMs stage via global_load_lds dwordx4 with a
// 2-phase double-buffered pipeline (stage t+1 before computing t; one
// __syncthreads per K-tile => loads overlap compute). gemm3 is K-split x4
// (grid 256 blocks) with fp32 partials reduced inside ln_o.
// FALLBACK (small ws): original verified kernel.

typedef unsigned short u16;
typedef unsigned int u32;
typedef __attribute__((ext_vector_type(8))) short short8;
typedef __attribute__((ext_vector_type(4))) float floatx4;

#define B_ROWS 1024
#define H_DIM 4096
#define D_DIM 1024
#define LDA_S 72   // padded As row stride (u16) for fallback kernel

__device__ __forceinline__ float bf2f(u16 v) {
  u32 u = ((u32)v) << 16;
  return __builtin_bit_cast(float, u);
}
__device__ __forceinline__ u16 f2bf(float f) {
  u32 u = __builtin_bit_cast(u32, f);
  u32 r = (u + 0x7fffu + ((u >> 16) & 1u)) >> 16;   // round-to-nearest-even
  return (u16)r;
}
__device__ __forceinline__ u32 pkbf(float lo, float hi) {
  return (u32)f2bf(lo) | ((u32)f2bf(hi) << 16);
}

// global -> LDS direct copy, 16B per lane. LDS dest = wave-uniform base +
// lane*16 (linear); global source is per-lane.
__device__ __forceinline__ void gload_lds16(const u16* g, u16* l) {
  __builtin_amdgcn_global_load_lds(
      (const __attribute__((address_space(1))) void*)g,
      (__attribute__((address_space(3))) void*)l, 16, 0, 0);
}

// ---------------- conversion kernels (fast path) ----------------

// Weights W (fp32 [K,N] row-major) -> tile images [nb][kt] (16KB each).
// Optional second matrix W1 appended in nb (nb >= nbHalf).
__launch_bounds__(256)
__global__ void conv_w_k(const float* __restrict__ W0, const float* __restrict__ W1,
                         u16* __restrict__ img, int ldb, int KT, int nbHalf) {
  const int nb = blockIdx.x;
  const int kt = blockIdx.y;
  const float* W = (nb < nbHalf) ? W0 : W1;
  const int nbl = (nb < nbHalf) ? nb : (nb - nbHalf);
  const float* src = W + (size_t)kt * 64 * ldb + (size_t)nbl * 128;
  u16* dst = img + ((size_t)nb * KT + kt) * 8192;
  const int t = threadIdx.x;
  const int n = t & 127;
  const int half = t >> 7;
#pragma unroll
  for (int pass = 0; pass < 4; ++pass) {
    const int kc = half * 4 + pass;
    const float* sp = src + (size_t)(kc * 8) * ldb + n;
    uint4 o;
    o.x = pkbf(sp[0],                 sp[(size_t)ldb]);
    o.y = pkbf(sp[(size_t)2 * ldb],   sp[(size_t)3 * ldb]);
    o.z = pkbf(sp[(size_t)4 * ldb],   sp[(size_t)5 * ldb]);
    o.w = pkbf(sp[(size_t)6 * ldb],   sp[(size_t)7 * ldb]);
    *(uint4*)(dst + (size_t)(kc * 128 + n) * 8) = o;
  }
}

// Activations x [1024,1024] and h [1024,4096] -> tile images [mb][kt].
// grid (80, 8): kt<16 -> x, else h.
__launch_bounds__(256)
__global__ void conv_xh_k(const float* __restrict__ x, const float* __restrict__ h,
                          u16* __restrict__ imgX, u16* __restrict__ imgH) {
  const int kt = blockIdx.x;
  const int mb = blockIdx.y;
  const float* src;
  u16* dst;
  int lda;
  if (kt < 16) {
    lda = 1024;
    src = x + (size_t)mb * 128 * lda + (size_t)kt * 64;
    dst = imgX + ((size_t)mb * 16 + kt) * 8192;
  } else {
    lda = 4096;
    src = h + (size_t)mb * 128 * lda + (size_t)(kt - 16) * 64;
    dst = imgH + ((size_t)mb * 64 + (kt - 16)) * 8192;
  }
  const int t = threadIdx.x;
  const int j = t & 127;
  const int half = t >> 7;
  const float* sp = src + (size_t)j * lda + half * 32;
#pragma unroll
  for (int pass = 0; pass < 4; ++pass) {
    const int kc = half * 4 + pass;
    const float4 a = *(const float4*)(sp + pass * 8);
    const float4 b = *(const float4*)(sp + pass * 8 + 4);
    uint4 o;
    o.x = pkbf(a.x, a.y);
    o.y = pkbf(a.z, a.w);
    o.z = pkbf(b.x, b.y);
    o.w = pkbf(b.z, b.w);
    *(uint4*)(dst + (size_t)(kc * 128 + j) * 8) = o;
  }
}

// ---------------- image GEMM (fast path, 2-phase dbuf) ----------------
// MODE 1: B=[Wu|Wr] imgs; first half -> u=sigmoid fp32 (outF linear);
//         second half -> rh=sigmoid*h bf16 -> imgRH tile layout (outB0).
// MODE 2: B=[Wg|Wup]; first -> g bf16 linear (outB0), second -> up (outB1).
// MODE 3: B=Wd img; K-split via blockIdx.z (4 x 16 tiles);
//         outF = partial sum fp32 (no bias) at outF + z*1M.
template <int MODE>
__launch_bounds__(256)
__global__ void gemm_img(const u16* __restrict__ A0, const u16* __restrict__ A1,
                         const u16* __restrict__ Bimg,
                         const float* __restrict__ bias0, const float* __restrict__ bias1,
                         const float* __restrict__ hglob,
                         float* __restrict__ outF, u16* __restrict__ outB0,
                         u16* __restrict__ outB1) {
  constexpr int KT = (MODE == 3) ? 16 : 80;       // K-tiles per block
  constexpr int KSPLIT = 16;                      // MODE1/2: tiles from A0 (x)
  constexpr int KT_B = (MODE == 3) ? 64 : 80;     // B image K-tiles per nb

  const int bx = blockIdx.x;
  const int by = blockIdx.y;
  const int kz = (MODE == 3) ? (int)blockIdx.z * 16 : 0;
  const int n0 = bx * 128;
  const int m0 = by * 128;
  const bool second = (MODE != 3) && (n0 >= 4096);
  const int ncol0 = second ? (n0 - 4096) : n0;

  __shared__ __align__(16) u16 As[2][8192];
  __shared__ __align__(16) u16 Bs[2][8192];

  const int t = threadIdx.x;
  const int w = t >> 6;
  const int lane = t & 63;
  const int q = lane >> 4;
  const int i16 = lane & 15;
  const int wm = (w >> 1) * 64;
  const int wn = (w & 1) * 64;

  floatx4 acc[4][4] = {};

  const u16* btile = Bimg + ((size_t)bx * KT_B + kz) * 8192;

  // stage K-tile kt into buffer buf (8 x 1KB chunks per wave, A and B)
  auto stage = [&](int kt, int buf) {
    const u16* a;
    if (MODE == 3) {
      a = A0 + ((size_t)by * 64 + kz + kt) * 8192;
    } else {
      a = (kt < KSPLIT) ? A0 + ((size_t)by * 16 + kt) * 8192
                        : A1 + ((size_t)by * 64 + (kt - KSPLIT)) * 8192;
    }
    const u16* b = btile + (size_t)kt * 8192;
    u16* As_ = &As[buf][0];
    u16* Bs_ = &Bs[buf][0];
#pragma unroll
    for (int i = 0; i < 4; ++i) {
      const int ch = (i * 4 + w) * 512;   // u16 offset of a 1KB chunk
      gload_lds16(a + ch + lane * 8, As_ + ch);
      gload_lds16(b + ch + lane * 8, Bs_ + ch);
    }
  };

  stage(0, 0);
  __syncthreads();                 // vmcnt(0) + barrier: buf0 ready
  int cur = 0;

  for (int kt = 0; kt < KT; ++kt) {
    if (kt + 1 < KT) stage(kt + 1, cur ^ 1);   // loads fly during compute
    // ---- MFMA: 2 k-steps of 32, 4x4 tiles of 16x16 per wave ----
#pragma unroll
    for (int s = 0; s < 2; ++s) {
      const int c = s * 4 + q;
      short8 av[4], bv[4];
#pragma unroll
      for (int tm = 0; tm < 4; ++tm)
        av[tm] = *(const short8*)(&As[cur][(size_t)(c * 128 + wm + tm * 16 + i16) * 8]);
#pragma unroll
      for (int tn = 0; tn < 4; ++tn)
        bv[tn] = *(const short8*)(&Bs[cur][(size_t)(c * 128 + wn + tn * 16 + i16) * 8]);
#pragma unroll
      for (int tm = 0; tm < 4; ++tm)
#pragma unroll
        for (int tn = 0; tn < 4; ++tn)
          acc[tm][tn] = __builtin_amdgcn_mfma_f32_16x16x32_bf16(av[tm], bv[tn], acc[tm][tn], 0, 0, 0);
    }
    __syncthreads();               // drains next-tile loads (post-compute) + barrier
    cur ^= 1;
  }

  // ---- epilogue ----
  const float* __restrict__ biasP = second ? bias1 : bias0;
  float* __restrict__ outP = (MODE == 3) ? outF + (size_t)blockIdx.z * (1024 * 1024) : outF;
#pragma unroll
  for (int tm = 0; tm < 4; ++tm) {
#pragma unroll
    for (int tn = 0; tn < 4; ++tn) {
      const int nloc = ncol0 + wn + tn * 16 + i16;
      const float b = (MODE == 3) ? 0.f : biasP[nloc];
      const int mbase = m0 + wm + tm * 16 + q * 4;
#pragma unroll
      for (int r = 0; r < 4; ++r) {
        const int m = mbase + r;
        const float v = acc[tm][tn][r] + b;
        if (MODE == 1) {
          const float sg = 1.f / (1.f + __expf(-v));
          if (!second) {
            outF[(size_t)m * 4096 + nloc] = sg;                  // u gate fp32
          } else {
            const float rh = sg * hglob[(size_t)m * 4096 + nloc];
            // write r*h into gemm2's A tile image (k = 1024 + nloc)
            const size_t tb = ((size_t)(m >> 7) * 64 + (nloc >> 6)) * 8192;
            outB0[tb + (size_t)((((nloc >> 3) & 7) * 128) + (m & 127)) * 8 + (nloc & 7)] = f2bf(rh);
          }
        } else if (MODE == 2) {
          if (!second) outB0[(size_t)m * 4096 + nloc] = f2bf(v);  // g pre-act
          else         outB1[(size_t)m * 4096 + nloc] = f2bf(v);  // up pre-act
        } else {
          outP[(size_t)m * 1024 + nloc] = v;                      // partial sum
        }
      }
    }
  }
}

// ---------------- fallback GEMM (previous verified kernel) ----------------
template <int MODE>
__launch_bounds__(256)
__global__ void gemm_k(const float* __restrict__ Af0, const float* __restrict__ Af1,
                       const u16* __restrict__ Ab,
                       const float* __restrict__ Bg0, const float* __restrict__ Bg1,
                       const float* __restrict__ bias0, const float* __restrict__ bias1,
                       const float* __restrict__ hglob,
                       float* __restrict__ outF, u16* __restrict__ outB0,
                       u16* __restrict__ outB1) {
  constexpr int K_TOT = (MODE == 3) ? 4096 : 5120;
  constexpr int KT = K_TOT / 64;
  constexpr int LDB = (MODE == 3) ? 1024 : 4096;

  const int n0 = blockIdx.x * 128;
  const int m0 = blockIdx.y * 128;
  const bool second = (MODE != 3) && (n0 >= 4096);
  const float* __restrict__ Bg = second ? Bg1 : Bg0;
  const int ncol0 = second ? (n0 - 4096) : n0;

  __shared__ __align__(16) u16 As[128 * LDA_S];
  __shared__ __align__(16) u16 Bs[64 * 128];

  const int t = threadIdx.x;
  const int w = t >> 6;
  const int lane = t & 63;
  const int q = lane >> 4;
  const int i16 = lane & 15;
  const int wm = (w >> 1) * 64;
  const int wn = (w & 1) * 64;

  floatx4 acc[4][4] = {};

  for (int kt = 0; kt < KT; ++kt) {
    const int k0 = kt * 64;
    const bool a_is_bf16 = (MODE == 2) && (k0 >= 1024);
    if (a_is_bf16) {
      const u16* Ag = Ab;
      const int lda = 4096;
      const int krel = k0 - 1024;
#pragma unroll
      for (int c = 0; c < 4; ++c) {
        const int p = c * 256 + t;
        const int row = p >> 3;
        const int cp = p & 7;
        const uint4 v = *(const uint4*)(Ag + (size_t)(m0 + row) * lda + krel + cp * 8);
        *(uint4*)(&As[row * LDA_S + cp * 8]) = v;
      }
    } else {
      const float* Ag;
      int lda, krel;
      if (MODE == 3)      { Ag = Af0; lda = 4096; krel = k0; }
      else if (k0 < 1024) { Ag = Af0; lda = 1024; krel = k0; }
      else                { Ag = Af1; lda = 4096; krel = k0 - 1024; }
#pragma unroll
      for (int c = 0; c < 8; ++c) {
        const int p = c * 256 + t;
        const int row = p >> 4;
        const int cp = p & 15;
        const float4 v = *(const float4*)(Ag + (size_t)(m0 + row) * lda + krel + cp * 4);
        ushort4 o;
        o.x = f2bf(v.x); o.y = f2bf(v.y); o.z = f2bf(v.z); o.w = f2bf(v.w);
        *(ushort4*)(&As[row * LDA_S + cp * 4]) = o;
      }
    }
#pragma unroll
    for (int cc = 0; cc < 2; ++cc) {
      const int c = 2 * w + cc;
      const float* bp = Bg + (size_t)(k0 + c * 8) * LDB + ncol0;
#pragma unroll
      for (int hn = 0; hn < 2; ++hn) {
        const int n = lane + hn * 64;
        const float* src = bp + n;
        u32 p0 = (u32)f2bf(src[0 * LDB]) | ((u32)f2bf(src[1 * LDB]) << 16);
        u32 p1 = (u32)f2bf(src[2 * LDB]) | ((u32)f2bf(src[3 * LDB]) << 16);
        u32 p2 = (u32)f2bf(src[4 * LDB]) | ((u32)f2bf(src[5 * LDB]) << 16);
        u32 p3 = (u32)f2bf(src[6 * LDB]) | ((u32)f2bf(src[7 * LDB]) << 16);
        *(uint4*)(&Bs[(size_t)(c * 128 + n) * 8]) = make_uint4(p0, p1, p2, p3);
      }
    }
    __syncthreads();
#pragma unroll
    for (int s = 0; s < 2; ++s) {
      short8 av[4], bv[4];
#pragma unroll
      for (int tm = 0; tm < 4; ++tm) {
        const int r = wm + tm * 16 + i16;
        av[tm] = *(const short8*)(&As[r * LDA_S + (s * 4 + q) * 8]);
      }
#pragma unroll
      for (int tn = 0; tn < 4; ++tn) {
        const int n = wn + tn * 16 + i16;
        const int c = s * 4 + q;
        bv[tn] = *(const short8*)(&Bs[(size_t)(c * 128 + n) * 8]);
      }
#pragma unroll
      for (int tm = 0; tm < 4; ++tm)
#pragma unroll
        for (int tn = 0; tn < 4; ++tn)
          acc[tm][tn] = __builtin_amdgcn_mfma_f32_16x16x32_bf16(av[tm], bv[tn], acc[tm][tn], 0, 0, 0);
    }
    __syncthreads();
  }

  const float* __restrict__ biasP = second ? bias1 : bias0;
  constexpr int LDO = (MODE == 3) ? 1024 : 4096;
#pragma unroll
  for (int tm = 0; tm < 4; ++tm) {
#pragma unroll
    for (int tn = 0; tn < 4; ++tn) {
      const int nloc = ncol0 + wn + tn * 16 + i16;
      const float b = biasP[nloc];
      const int mbase = m0 + wm + tm * 16 + q * 4;
#pragma unroll
      for (int r = 0; r < 4; ++r) {
        const int m = mbase + r;
        const float v = acc[tm][tn][r] + b;
        const size_t oidx = (size_t)m * LDO + nloc;
        if (MODE == 1) {
          const float sg = 1.f / (1.f + __expf(-v));
          if (!second) outF[oidx] = sg;
          else         outB0[oidx] = f2bf(sg * hglob[oidx]);
        } else if (MODE == 2) {
          if (!second) outB0[oidx] = f2bf(v);
          else         outB1[oidx] = f2bf(v);
        } else {
          outF[oidx] = v;
        }
      }
    }
  }
}

// ---------------- LayerNorms ----------------
// u_f (fp32) ALIASES out (in-place, same offsets): reads precede barrier,
// writes after; one block owns one row. imgNH (may be null): new_h bf16
// tile-image for gemm3's A.
__launch_bounds__(256)
__global__ void ln_h_k(const float* u_f, const u16* __restrict__ wsg,
                       const u16* __restrict__ wsup, const float* __restrict__ h,
                       const float* __restrict__ gamma, const float* __restrict__ beta,
                       float* out, u16* __restrict__ imgNH) {
  const int row = blockIdx.x, t = threadIdx.x;
  const size_t base = (size_t)row * H_DIM;
  const int i0 = t * 16;
  float tv[16];
  float s = 0.f, s2 = 0.f;
#pragma unroll
  for (int j = 0; j < 16; ++j) {
    const int idx = i0 + j;
    const float u = u_f[base + idx];
    const float g = bf2f(wsg[base + idx]);
    const float up = bf2f(wsup[base + idx]);
    const float hh = h[base + idx];
    const float sw = (g / (1.f + __expf(-g))) * up;   // silu(g)*up
    const float x = (2.f - u) * hh + u * sw;
    tv[j] = x; s += x; s2 += x * x;
  }
#pragma unroll
  for (int off = 32; off; off >>= 1) {
    s += __shfl_down(s, off);
    s2 += __shfl_down(s2, off);
  }
  __shared__ float red[8];
  const int w = t >> 6, lane = t & 63;
  if (lane == 0) { red[w] = s; red[4 + w] = s2; }
  __syncthreads();
  const float S = red[0] + red[1] + red[2] + red[3];
  const float S2 = red[4] + red[5] + red[6] + red[7];
  const float mean = S * (1.f / (float)H_DIM);
  const float var = fmaxf(S2 * (1.f / (float)H_DIM) - mean * mean, 0.f);
  const float rstd = rsqrtf(var + 1e-3f);
#pragma unroll
  for (int cc = 0; cc < 2; ++cc) {
    float o[8];
#pragma unroll
    for (int jj = 0; jj < 8; ++jj) {
      const int idx = i0 + cc * 8 + jj;
      o[jj] = (tv[cc * 8 + jj] - mean) * rstd * gamma[idx] + beta[idx];
      out[base + idx] = o[jj];
    }
    if (imgNH) {
      const int idx8 = i0 + cc * 8;
      uint4 v;
      v.x = pkbf(o[0], o[1]);
      v.y = pkbf(o[2], o[3]);
      v.z = pkbf(o[4], o[5]);
      v.w = pkbf(o[6], o[7]);
      *(uint4*)(&imgNH[((size_t)(row >> 7) * 64 + (idx8 >> 6)) * 8192 +
                       (size_t)((((idx8 >> 3) & 7) * 128) + (row & 127)) * 8]) = v;
    }
  }
}

// Fast-path final LN: sum 4 fp32 K-split partials + bias, LayerNorm, write out.
__launch_bounds__(256)
__global__ void ln_o_k(const float* __restrict__ part, const float* __restrict__ bias,
                       const float* __restrict__ gamma, const float* __restrict__ beta,
                       float* __restrict__ out) {
  const int row = blockIdx.x, t = threadIdx.x;
  const size_t base = (size_t)row * D_DIM;
  const int i0 = t * 4;
  constexpr size_t PSTRIDE = (size_t)1024 * 1024;
  float tv[4];
  float s = 0.f, s2 = 0.f;
#pragma unroll
  for (int j = 0; j < 4; ++j) {
    const size_t idx = base + i0 + j;
    const float x = part[idx] + part[idx + PSTRIDE] + part[idx + 2 * PSTRIDE] +
                    part[idx + 3 * PSTRIDE] + bias[i0 + j];
    tv[j] = x; s += x; s2 += x * x;
  }
#pragma unroll
  for (int off = 32; off; off >>= 1) {
    s += __shfl_down(s, off);
    s2 += __shfl_down(s2, off);
  }
  __shared__ float red[8];
  const int w = t >> 6, lane = t & 63;
  if (lane == 0) { red[w] = s; red[4 + w] = s2; }
  __syncthreads();
  const float S = red[0] + red[1] + red[2] + red[3];
  const float S2 = red[4] + red[5] + red[6] + red[7];
  const float mean = S * (1.f / (float)D_DIM);
  const float var = fmaxf(S2 * (1.f / (float)D_DIM) - mean * mean, 0.f);
  const float rstd = rsqrtf(var + 1e-3f);
#pragma unroll
  for (int j = 0; j < 4; ++j) {
    const int idx = i0 + j;
    out[base + idx] = (tv[j] - mean) * rstd * gamma[idx] + beta[idx];
  }
}

// Fallback final LN: in-place over fp32 region (original).
__launch_bounds__(256)
__global__ void ln_o_fb(float* io, const float* __restrict__ gamma,
                        const float* __restrict__ beta) {
  const int row = blockIdx.x, t = threadIdx.x;
  const size_t base = (size_t)row * D_DIM;
  const int i0 = t * 4;
  float tv[4];
  float s = 0.f, s2 = 0.f;
#pragma unroll
  for (int j = 0; j < 4; ++j) {
    const float x = io[base + i0 + j];
    tv[j] = x; s += x; s2 += x * x;
  }
#pragma unroll
  for (int off = 32; off; off >>= 1) {
    s += __shfl_down(s, off);
    s2 += __shfl_down(s2, off);
  }
  __shared__ float red[8];
  const int w = t >> 6, lane = t & 63;
  if (lane == 0) { red[w] = s; red[4 + w] = s2; }
  __syncthreads();
  const float S = red[0] + red[1] + red[2] + red[3];
  const float S2 = red[4] + red[5] + red[6] + red[7];
  const float mean = S * (1.f / (float)D_DIM);
  const float var = fmaxf(S2 * (1.f / (float)D_DIM) - mean * mean, 0.f);
  const float rstd = rsqrtf(var + 1e-3f);
#pragma unroll
  for (int j = 0; j < 4; ++j) {
    const int idx = i0 + j;
    io[base + idx] = (tv[j] - mean) * rstd * gamma[idx] + beta[idx];
  }
}

extern "C" void kernel_launch(void* const* d_in, const int* in_sizes, int n_in,
                              void* d_out, int out_size, void* d_ws, size_t ws_size,
                              hipStream_t stream) {
  (void)in_sizes; (void)n_in; (void)out_size;
  const float* x       = (const float*)d_in[0];
  const float* h       = (const float*)d_in[1];
  const float* W_u     = (const float*)d_in[2];
  const float* b_u     = (const float*)d_in[3];
  const float* W_r     = (const float*)d_in[4];
  const float* b_r     = (const float*)d_in[5];
  const float* W_g     = (const float*)d_in[6];
  const float* b_g     = (const float*)d_in[7];
  const float* W_up    = (const float*)d_in[8];
  const float* b_up    = (const float*)d_in[9];
  const float* W_d     = (const float*)d_in[10];
  const float* b_d     = (const float*)d_in[11];
  const float* gamma_h = (const float*)d_in[12];
  const float* beta_h  = (const float*)d_in[13];
  const float* gamma_o = (const float*)d_in[14];
  const float* beta_o  = (const float*)d_in[15];

  float* out_final = (float*)d_out;                              // [B,D] fp32
  float* out_newh  = (float*)d_out + (size_t)B_ROWS * D_DIM;     // [B,H] fp32
  float* u_buf = out_newh;   // u gate fp32 parked in d_out newh region
  float* o_pre = out_final;  // fallback: GEMM3 pre-act fp32 in d_out region

  dim3 blk(256);

  // ---- fast-path workspace layout (bytes) ----
  const size_t SZ_W  = (size_t)64 * 80 * 16384;   // 80 MiB: [Wu|Wr] / [Wg|Wup] / Wd imgs
  const size_t SZ_X  = (size_t)8 * 16 * 16384;    //  2 MiB
  const size_t SZ_H  = (size_t)8 * 64 * 16384;    //  8 MiB (also reused as imgNH)
  const size_t SZ_RH = SZ_H;
  const size_t SZ_G  = (size_t)B_ROWS * H_DIM * 2;  // 8 MiB
  const size_t SZ_UP = SZ_G;                        // 8 MiB
  const size_t NEED  = SZ_W + SZ_X + SZ_H + SZ_RH + SZ_G + SZ_UP;  // 114 MiB

  if (ws_size >= NEED) {
    char* ws = (char*)d_ws;
    u16* imgW  = (u16*)(ws);
    u16* imgX  = (u16*)(ws + SZ_W);
    u16* imgH  = (u16*)(ws + SZ_W + SZ_X);
    u16* imgNH = imgH;                             // imgH dead after gemm1
    u16* imgRH = (u16*)(ws + SZ_W + SZ_X + SZ_H);
    u16* ws_g  = (u16*)(ws + SZ_W + SZ_X + SZ_H + SZ_RH);
    u16* ws_up = (u16*)(ws + SZ_W + SZ_X + SZ_H + SZ_RH + SZ_G);
    // gemm3 partials (16 MiB fp32) reuse ws_g+ws_up (dead after ln_h)
    float* part = (float*)ws_g;

    conv_xh_k<<<dim3(80, 8), blk, 0, stream>>>(x, h, imgX, imgH);
    conv_w_k<<<dim3(64, 80), blk, 0, stream>>>(W_u, W_r, imgW, 4096, 80, 32);
    gemm_img<1><<<dim3(64, 8), blk, 0, stream>>>(imgX, imgH, imgW, b_u, b_r, h,
                                                 u_buf, imgRH, nullptr);
    conv_w_k<<<dim3(64, 80), blk, 0, stream>>>(W_g, W_up, imgW, 4096, 80, 32);
    gemm_img<2><<<dim3(64, 8), blk, 0, stream>>>(imgX, imgRH, imgW, b_g, b_up, nullptr,
                                                 nullptr, ws_g, ws_up);
    ln_h_k<<<dim3(B_ROWS), blk, 0, stream>>>(u_buf, ws_g, ws_up, h, gamma_h, beta_h,
                                             out_newh, imgNH);
    conv_w_k<<<dim3(8, 64), blk, 0, stream>>>(W_d, nullptr, imgW, 1024, 64, 8);
    gemm_img<3><<<dim3(8, 8, 4), blk, 0, stream>>>(imgNH, imgNH, imgW, nullptr, nullptr,
                                                   nullptr, part, nullptr, nullptr);
    ln_o_k<<<dim3(B_ROWS), blk, 0, stream>>>(part, b_d, gamma_o, beta_o, out_final);
  } else {
    // fallback: original verified path (24 MB workspace)
    char* ws = (char*)d_ws;
    u16* ws_rh = (u16*)(ws);
    u16* ws_g  = (u16*)(ws + (size_t)8 * 1024 * 1024);
    u16* ws_up = (u16*)(ws + (size_t)16 * 1024 * 1024);

    gemm_k<1><<<dim3(64, 8), blk, 0, stream>>>(x, h, nullptr, W_u, W_r, b_u, b_r, h,
                                               u_buf, ws_rh, nullptr);
    gemm_k<2><<<dim3(64, 8), blk, 0, stream>>>(x, nullptr, ws_rh, W_g, W_up, b_g, b_up,
                                               nullptr, nullptr, ws_g, ws_up);
    ln_h_k<<<dim3(B_ROWS), blk, 0, stream>>>(u_buf, ws_g, ws_up, h, gamma_h, beta_h,
                                             out_newh, nullptr);
    gemm_k<3><<<dim3(8, 8), blk, 0, stream>>>(out_newh, nullptr, nullptr, W_d, nullptr,
                                              b_d, nullptr, nullptr, o_pre, nullptr, nullptr);
    ln_o_fb<<<dim3(B_ROWS), blk, 0, stream>>>(o_pre, gamma_o, beta_o);
  }
}

// Round 5
// 618.090 us; speedup vs baseline: 1.2036x; 1.0411x over previous
//
#include <hip/hip_runtime.h>
#include <hip/hip_bf16.h>
#include <math.h>

// RecurrentFFN: B=1024, D=1024, H=4096, C=5120.
// FUSED PATH (ws >= 194MiB): bf16 tile images; the NEXT gemm's weight
// conversion runs as extra blocks appended to the CURRENT gemm's grid
// (heterogeneous dispatch). Fused gemm uses 32KB single-buffer LDS so conv
// blocks co-reside (2 gemm + 3 conv blocks/CU) and fill gemm latency stalls.
// SEQ PATH (ws >= 114MiB): round-3 verified dbuf pipeline, sequential convs.
// LEGACY (small ws): original in-gemm-conversion kernel.

typedef unsigned short u16;
typedef unsigned int u32;
typedef __attribute__((ext_vector_type(8))) short short8;
typedef __attribute__((ext_vector_type(4))) float floatx4;

#define B_ROWS 1024
#define H_DIM 4096
#define D_DIM 1024
#define LDA_S 72   // padded As row stride (u16) for legacy kernel

__device__ __forceinline__ float bf2f(u16 v) {
  u32 u = ((u32)v) << 16;
  return __builtin_bit_cast(float, u);
}
__device__ __forceinline__ u16 f2bf(float f) {
  u32 u = __builtin_bit_cast(u32, f);
  u32 r = (u + 0x7fffu + ((u >> 16) & 1u)) >> 16;   // round-to-nearest-even
  return (u16)r;
}
__device__ __forceinline__ u32 pkbf(float lo, float hi) {
  return (u32)f2bf(lo) | ((u32)f2bf(hi) << 16);
}

// global -> LDS direct copy, 16B per lane. LDS dest = wave-uniform base +
// lane*16 (linear); global source is per-lane.
__device__ __forceinline__ void gload_lds16(const u16* g, u16* l) {
  __builtin_amdgcn_global_load_lds(
      (const __attribute__((address_space(1))) void*)g,
      (__attribute__((address_space(3))) void*)l, 16, 0, 0);
}

// ---------------- weight conversion body (shared) ----------------
// W (fp32 [K,N] row-major) -> tile image tile[(kc*128+n)*8+kr] = bf16(W[k0+kc*8+kr][n0+n]).
// 256 threads: t -> n2 = 2*(t&63), kcg = t>>6 (2 kc each). float2 reads
// (512B/wave per row-segment), 32B-contiguous writes per lane.
__device__ __forceinline__ void conv_w_body(int nb, int kt,
                                            const float* __restrict__ W0,
                                            const float* __restrict__ W1,
                                            u16* __restrict__ img, int ldb,
                                            int KT, int nbHalf) {
  const float* W = (nb < nbHalf) ? W0 : W1;
  const int nbl = (nb < nbHalf) ? nb : (nb - nbHalf);
  const float* src = W + (size_t)kt * 64 * ldb + (size_t)nbl * 128;
  u16* dst = img + ((size_t)nb * KT + kt) * 8192;
  const int t = threadIdx.x;
  const int n2 = (t & 63) * 2;
  const int kcg = t >> 6;
#pragma unroll
  for (int kk = 0; kk < 2; ++kk) {
    const int kc = kcg * 2 + kk;
    const float* sp = src + (size_t)(kc * 8) * ldb + n2;
    float2 r[8];
#pragma unroll
    for (int c = 0; c < 8; ++c) r[c] = *(const float2*)(sp + (size_t)c * ldb);
    uint4 o0, o1;
    o0.x = pkbf(r[0].x, r[1].x); o0.y = pkbf(r[2].x, r[3].x);
    o0.z = pkbf(r[4].x, r[5].x); o0.w = pkbf(r[6].x, r[7].x);
    o1.x = pkbf(r[0].y, r[1].y); o1.y = pkbf(r[2].y, r[3].y);
    o1.z = pkbf(r[4].y, r[5].y); o1.w = pkbf(r[6].y, r[7].y);
    u16* dp = dst + (size_t)(kc * 128 + n2) * 8;
    *(uint4*)(dp) = o0;
    *(uint4*)(dp + 8) = o1;
  }
}

__launch_bounds__(256)
__global__ void conv_w_k(const float* __restrict__ W0, const float* __restrict__ W1,
                         u16* __restrict__ img, int ldb, int KT, int nbHalf) {
  conv_w_body(blockIdx.x, blockIdx.y, W0, W1, img, ldb, KT, nbHalf);
}

// Activations x [1024,1024] and h [1024,4096] -> tile images [mb][kt].
// grid (80, 8): kt<16 -> x, else h.
__launch_bounds__(256)
__global__ void conv_xh_k(const float* __restrict__ x, const float* __restrict__ h,
                          u16* __restrict__ imgX, u16* __restrict__ imgH) {
  const int kt = blockIdx.x;
  const int mb = blockIdx.y;
  const float* src;
  u16* dst;
  int lda;
  if (kt < 16) {
    lda = 1024;
    src = x + (size_t)mb * 128 * lda + (size_t)kt * 64;
    dst = imgX + ((size_t)mb * 16 + kt) * 8192;
  } else {
    lda = 4096;
    src = h + (size_t)mb * 128 * lda + (size_t)(kt - 16) * 64;
    dst = imgH + ((size_t)mb * 64 + (kt - 16)) * 8192;
  }
  const int t = threadIdx.x;
  const int j = t & 127;
  const int half = t >> 7;
  const float* sp = src + (size_t)j * lda + half * 32;
#pragma unroll
  for (int pass = 0; pass < 4; ++pass) {
    const int kc = half * 4 + pass;
    const float4 a = *(const float4*)(sp + pass * 8);
    const float4 b = *(const float4*)(sp + pass * 8 + 4);
    uint4 o;
    o.x = pkbf(a.x, a.y);
    o.y = pkbf(a.z, a.w);
    o.z = pkbf(b.x, b.y);
    o.w = pkbf(b.z, b.w);
    *(uint4*)(dst + (size_t)(kc * 128 + j) * 8) = o;
  }
}

// ---------------- fused gemm + conv (heterogeneous grid, 32KB LDS) -------
// Blocks [0, ngemm): gemm (bx = id&63, by = id>>6). Blocks >= ngemm: weight
// conversion for the NEXT gemm (nb = cid & (2^sh-1), kt = cid >> sh).
// MODE 1: B=[Wu|Wr]; first half -> u=sigmoid fp32; second -> rh bf16 -> imgRH.
// MODE 2: B=[Wg|Wup]; first -> g bf16 linear, second -> up bf16 linear.
template <int MODE>
__launch_bounds__(256)
__global__ void gemm_conv(const u16* __restrict__ A0, const u16* __restrict__ A1,
                          const u16* __restrict__ Bimg,
                          const float* __restrict__ bias0, const float* __restrict__ bias1,
                          const float* __restrict__ hglob,
                          float* __restrict__ outF, u16* __restrict__ outB0,
                          u16* __restrict__ outB1, int ngemm,
                          const float* __restrict__ cW0, const float* __restrict__ cW1,
                          u16* __restrict__ cimg, int cldb, int cKT, int cnbHalf,
                          int csh) {
  __shared__ __align__(16) u16 As[8192];
  __shared__ __align__(16) u16 Bs[8192];

  const int fid = blockIdx.x;
  if (fid >= ngemm) {
    const int cid = fid - ngemm;
    conv_w_body(cid & ((1 << csh) - 1), cid >> csh, cW0, cW1, cimg, cldb, cKT, cnbHalf);
    return;
  }

  constexpr int KT = 80;
  constexpr int KSPLIT = 16;

  const int bx = fid & 63;
  const int by = fid >> 6;
  const int n0 = bx * 128;
  const int m0 = by * 128;
  const bool second = (n0 >= 4096);
  const int ncol0 = second ? (n0 - 4096) : n0;

  const int t = threadIdx.x;
  const int w = t >> 6;
  const int lane = t & 63;
  const int q = lane >> 4;
  const int i16 = lane & 15;
  const int wm = (w >> 1) * 64;
  const int wn = (w & 1) * 64;

  floatx4 acc[4][4] = {};

  const u16* btile = Bimg + (size_t)bx * KT * 8192;

  for (int kt = 0; kt < KT; ++kt) {
    const u16* a = (kt < KSPLIT) ? A0 + ((size_t)by * 16 + kt) * 8192
                                 : A1 + ((size_t)by * 64 + (kt - KSPLIT)) * 8192;
    const u16* b = btile + (size_t)kt * 8192;
#pragma unroll
    for (int i = 0; i < 4; ++i) {
      const int ch = (i * 4 + w) * 512;   // u16 offset of a 1KB chunk
      gload_lds16(a + ch + lane * 8, &As[ch]);
      gload_lds16(b + ch + lane * 8, &Bs[ch]);
    }
    __syncthreads();
#pragma unroll
    for (int s = 0; s < 2; ++s) {
      const int c = s * 4 + q;
      short8 av[4], bv[4];
#pragma unroll
      for (int tm = 0; tm < 4; ++tm)
        av[tm] = *(const short8*)(&As[(size_t)(c * 128 + wm + tm * 16 + i16) * 8]);
#pragma unroll
      for (int tn = 0; tn < 4; ++tn)
        bv[tn] = *(const short8*)(&Bs[(size_t)(c * 128 + wn + tn * 16 + i16) * 8]);
#pragma unroll
      for (int tm = 0; tm < 4; ++tm)
#pragma unroll
        for (int tn = 0; tn < 4; ++tn)
          acc[tm][tn] = __builtin_amdgcn_mfma_f32_16x16x32_bf16(av[tm], bv[tn], acc[tm][tn], 0, 0, 0);
    }
    __syncthreads();
  }

  const float* __restrict__ biasP = second ? bias1 : bias0;
#pragma unroll
  for (int tm = 0; tm < 4; ++tm) {
#pragma unroll
    for (int tn = 0; tn < 4; ++tn) {
      const int nloc = ncol0 + wn + tn * 16 + i16;
      const float b = biasP[nloc];
      const int mbase = m0 + wm + tm * 16 + q * 4;
#pragma unroll
      for (int r = 0; r < 4; ++r) {
        const int m = mbase + r;
        const float v = acc[tm][tn][r] + b;
        if (MODE == 1) {
          const float sg = 1.f / (1.f + __expf(-v));
          if (!second) {
            outF[(size_t)m * 4096 + nloc] = sg;                  // u gate fp32
          } else {
            const float rh = sg * hglob[(size_t)m * 4096 + nloc];
            const size_t tb = ((size_t)(m >> 7) * 64 + (nloc >> 6)) * 8192;
            outB0[tb + (size_t)((((nloc >> 3) & 7) * 128) + (m & 127)) * 8 + (nloc & 7)] = f2bf(rh);
          }
        } else {
          if (!second) outB0[(size_t)m * 4096 + nloc] = f2bf(v);  // g pre-act
          else         outB1[(size_t)m * 4096 + nloc] = f2bf(v);  // up pre-act
        }
      }
    }
  }
}

// ---------------- image GEMM (sequential path, dbuf; + MODE3 K-split) ----
template <int MODE>
__launch_bounds__(256)
__global__ void gemm_img(const u16* __restrict__ A0, const u16* __restrict__ A1,
                         const u16* __restrict__ Bimg,
                         const float* __restrict__ bias0, const float* __restrict__ bias1,
                         const float* __restrict__ hglob,
                         float* __restrict__ outF, u16* __restrict__ outB0,
                         u16* __restrict__ outB1) {
  constexpr int KT = (MODE == 3) ? 16 : 80;
  constexpr int KSPLIT = 16;
  constexpr int KT_B = (MODE == 3) ? 64 : 80;

  const int bx = blockIdx.x;
  const int by = blockIdx.y;
  const int kz = (MODE == 3) ? (int)blockIdx.z * 16 : 0;
  const int n0 = bx * 128;
  const int m0 = by * 128;
  const bool second = (MODE != 3) && (n0 >= 4096);
  const int ncol0 = second ? (n0 - 4096) : n0;

  __shared__ __align__(16) u16 As[2][8192];
  __shared__ __align__(16) u16 Bs[2][8192];

  const int t = threadIdx.x;
  const int w = t >> 6;
  const int lane = t & 63;
  const int q = lane >> 4;
  const int i16 = lane & 15;
  const int wm = (w >> 1) * 64;
  const int wn = (w & 1) * 64;

  floatx4 acc[4][4] = {};

  const u16* btile = Bimg + ((size_t)bx * KT_B + kz) * 8192;

  auto stage = [&](int kt, int buf) {
    const u16* a;
    if (MODE == 3) {
      a = A0 + ((size_t)by * 64 + kz + kt) * 8192;
    } else {
      a = (kt < KSPLIT) ? A0 + ((size_t)by * 16 + kt) * 8192
                        : A1 + ((size_t)by * 64 + (kt - KSPLIT)) * 8192;
    }
    const u16* b = btile + (size_t)kt * 8192;
    u16* As_ = &As[buf][0];
    u16* Bs_ = &Bs[buf][0];
#pragma unroll
    for (int i = 0; i < 4; ++i) {
      const int ch = (i * 4 + w) * 512;
      gload_lds16(a + ch + lane * 8, As_ + ch);
      gload_lds16(b + ch + lane * 8, Bs_ + ch);
    }
  };

  stage(0, 0);
  __syncthreads();
  int cur = 0;

  for (int kt = 0; kt < KT; ++kt) {
    if (kt + 1 < KT) stage(kt + 1, cur ^ 1);
#pragma unroll
    for (int s = 0; s < 2; ++s) {
      const int c = s * 4 + q;
      short8 av[4], bv[4];
#pragma unroll
      for (int tm = 0; tm < 4; ++tm)
        av[tm] = *(const short8*)(&As[cur][(size_t)(c * 128 + wm + tm * 16 + i16) * 8]);
#pragma unroll
      for (int tn = 0; tn < 4; ++tn)
        bv[tn] = *(const short8*)(&Bs[cur][(size_t)(c * 128 + wn + tn * 16 + i16) * 8]);
#pragma unroll
      for (int tm = 0; tm < 4; ++tm)
#pragma unroll
        for (int tn = 0; tn < 4; ++tn)
          acc[tm][tn] = __builtin_amdgcn_mfma_f32_16x16x32_bf16(av[tm], bv[tn], acc[tm][tn], 0, 0, 0);
    }
    __syncthreads();
    cur ^= 1;
  }

  const float* __restrict__ biasP = second ? bias1 : bias0;
  float* __restrict__ outP = (MODE == 3) ? outF + (size_t)blockIdx.z * (1024 * 1024) : outF;
#pragma unroll
  for (int tm = 0; tm < 4; ++tm) {
#pragma unroll
    for (int tn = 0; tn < 4; ++tn) {
      const int nloc = ncol0 + wn + tn * 16 + i16;
      const float b = (MODE == 3) ? 0.f : biasP[nloc];
      const int mbase = m0 + wm + tm * 16 + q * 4;
#pragma unroll
      for (int r = 0; r < 4; ++r) {
        const int m = mbase + r;
        const float v = acc[tm][tn][r] + b;
        if (MODE == 1) {
          const float sg = 1.f / (1.f + __expf(-v));
          if (!second) {
            outF[(size_t)m * 4096 + nloc] = sg;
          } else {
            const float rh = sg * hglob[(size_t)m * 4096 + nloc];
            const size_t tb = ((size_t)(m >> 7) * 64 + (nloc >> 6)) * 8192;
            outB0[tb + (size_t)((((nloc >> 3) & 7) * 128) + (m & 127)) * 8 + (nloc & 7)] = f2bf(rh);
          }
        } else if (MODE == 2) {
          if (!second) outB0[(size_t)m * 4096 + nloc] = f2bf(v);
          else         outB1[(size_t)m * 4096 + nloc] = f2bf(v);
        } else {
          outP[(size_t)m * 1024 + nloc] = v;
        }
      }
    }
  }
}

// ---------------- legacy fallback GEMM ----------------
template <int MODE>
__launch_bounds__(256)
__global__ void gemm_k(const float* __restrict__ Af0, const float* __restrict__ Af1,
                       const u16* __restrict__ Ab,
                       const float* __restrict__ Bg0, const float* __restrict__ Bg1,
                       const float* __restrict__ bias0, const float* __restrict__ bias1,
                       const float* __restrict__ hglob,
                       float* __restrict__ outF, u16* __restrict__ outB0,
                       u16* __restrict__ outB1) {
  constexpr int K_TOT = (MODE == 3) ? 4096 : 5120;
  constexpr int KT = K_TOT / 64;
  constexpr int LDB = (MODE == 3) ? 1024 : 4096;

  const int n0 = blockIdx.x * 128;
  const int m0 = blockIdx.y * 128;
  const bool second = (MODE != 3) && (n0 >= 4096);
  const float* __restrict__ Bg = second ? Bg1 : Bg0;
  const int ncol0 = second ? (n0 - 4096) : n0;

  __shared__ __align__(16) u16 As[128 * LDA_S];
  __shared__ __align__(16) u16 Bs[64 * 128];

  const int t = threadIdx.x;
  const int w = t >> 6;
  const int lane = t & 63;
  const int q = lane >> 4;
  const int i16 = lane & 15;
  const int wm = (w >> 1) * 64;
  const int wn = (w & 1) * 64;

  floatx4 acc[4][4] = {};

  for (int kt = 0; kt < KT; ++kt) {
    const int k0 = kt * 64;
    const bool a_is_bf16 = (MODE == 2) && (k0 >= 1024);
    if (a_is_bf16) {
      const u16* Ag = Ab;
      const int lda = 4096;
      const int krel = k0 - 1024;
#pragma unroll
      for (int c = 0; c < 4; ++c) {
        const int p = c * 256 + t;
        const int row = p >> 3;
        const int cp = p & 7;
        const uint4 v = *(const uint4*)(Ag + (size_t)(m0 + row) * lda + krel + cp * 8);
        *(uint4*)(&As[row * LDA_S + cp * 8]) = v;
      }
    } else {
      const float* Ag;
      int lda, krel;
      if (MODE == 3)      { Ag = Af0; lda = 4096; krel = k0; }
      else if (k0 < 1024) { Ag = Af0; lda = 1024; krel = k0; }
      else                { Ag = Af1; lda = 4096; krel = k0 - 1024; }
#pragma unroll
      for (int c = 0; c < 8; ++c) {
        const int p = c * 256 + t;
        const int row = p >> 4;
        const int cp = p & 15;
        const float4 v = *(const float4*)(Ag + (size_t)(m0 + row) * lda + krel + cp * 4);
        ushort4 o;
        o.x = f2bf(v.x); o.y = f2bf(v.y); o.z = f2bf(v.z); o.w = f2bf(v.w);
        *(ushort4*)(&As[row * LDA_S + cp * 4]) = o;
      }
    }
#pragma unroll
    for (int cc = 0; cc < 2; ++cc) {
      const int c = 2 * w + cc;
      const float* bp = Bg + (size_t)(k0 + c * 8) * LDB + ncol0;
#pragma unroll
      for (int hn = 0; hn < 2; ++hn) {
        const int n = lane + hn * 64;
        const float* src = bp + n;
        u32 p0 = (u32)f2bf(src[0 * LDB]) | ((u32)f2bf(src[1 * LDB]) << 16);
        u32 p1 = (u32)f2bf(src[2 * LDB]) | ((u32)f2bf(src[3 * LDB]) << 16);
        u32 p2 = (u32)f2bf(src[4 * LDB]) | ((u32)f2bf(src[5 * LDB]) << 16);
        u32 p3 = (u32)f2bf(src[6 * LDB]) | ((u32)f2bf(src[7 * LDB]) << 16);
        *(uint4*)(&Bs[(size_t)(c * 128 + n) * 8]) = make_uint4(p0, p1, p2, p3);
      }
    }
    __syncthreads();
#pragma unroll
    for (int s = 0; s < 2; ++s) {
      short8 av[4], bv[4];
#pragma unroll
      for (int tm = 0; tm < 4; ++tm) {
        const int r = wm + tm * 16 + i16;
        av[tm] = *(const short8*)(&As[r * LDA_S + (s * 4 + q) * 8]);
      }
#pragma unroll
      for (int tn = 0; tn < 4; ++tn) {
        const int n = wn + tn * 16 + i16;
        const int c = s * 4 + q;
        bv[tn] = *(const short8*)(&Bs[(size_t)(c * 128 + n) * 8]);
      }
#pragma unroll
      for (int tm = 0; tm < 4; ++tm)
#pragma unroll
        for (int tn = 0; tn < 4; ++tn)
          acc[tm][tn] = __builtin_amdgcn_mfma_f32_16x16x32_bf16(av[tm], bv[tn], acc[tm][tn], 0, 0, 0);
    }
    __syncthreads();
  }

  const float* __restrict__ biasP = second ? bias1 : bias0;
  constexpr int LDO = (MODE == 3) ? 1024 : 4096;
#pragma unroll
  for (int tm = 0; tm < 4; ++tm) {
#pragma unroll
    for (int tn = 0; tn < 4; ++tn) {
      const int nloc = ncol0 + wn + tn * 16 + i16;
      const float b = biasP[nloc];
      const int mbase = m0 + wm + tm * 16 + q * 4;
#pragma unroll
      for (int r = 0; r < 4; ++r) {
        const int m = mbase + r;
        const float v = acc[tm][tn][r] + b;
        const size_t oidx = (size_t)m * LDO + nloc;
        if (MODE == 1) {
          const float sg = 1.f / (1.f + __expf(-v));
          if (!second) outF[oidx] = sg;
          else         outB0[oidx] = f2bf(sg * hglob[oidx]);
        } else if (MODE == 2) {
          if (!second) outB0[oidx] = f2bf(v);
          else         outB1[oidx] = f2bf(v);
        } else {
          outF[oidx] = v;
        }
      }
    }
  }
}

// ---------------- LayerNorms ----------------
__launch_bounds__(256)
__global__ void ln_h_k(const float* u_f, const u16* __restrict__ wsg,
                       const u16* __restrict__ wsup, const float* __restrict__ h,
                       const float* __restrict__ gamma, const float* __restrict__ beta,
                       float* out, u16* __restrict__ imgNH) {
  const int row = blockIdx.x, t = threadIdx.x;
  const size_t base = (size_t)row * H_DIM;
  const int i0 = t * 16;
  float tv[16];
  float s = 0.f, s2 = 0.f;
#pragma unroll
  for (int j = 0; j < 16; ++j) {
    const int idx = i0 + j;
    const float u = u_f[base + idx];
    const float g = bf2f(wsg[base + idx]);
    const float up = bf2f(wsup[base + idx]);
    const float hh = h[base + idx];
    const float sw = (g / (1.f + __expf(-g))) * up;   // silu(g)*up
    const float x = (2.f - u) * hh + u * sw;
    tv[j] = x; s += x; s2 += x * x;
  }
#pragma unroll
  for (int off = 32; off; off >>= 1) {
    s += __shfl_down(s, off);
    s2 += __shfl_down(s2, off);
  }
  __shared__ float red[8];
  const int w = t >> 6, lane = t & 63;
  if (lane == 0) { red[w] = s; red[4 + w] = s2; }
  __syncthreads();
  const float S = red[0] + red[1] + red[2] + red[3];
  const float S2 = red[4] + red[5] + red[6] + red[7];
  const float mean = S * (1.f / (float)H_DIM);
  const float var = fmaxf(S2 * (1.f / (float)H_DIM) - mean * mean, 0.f);
  const float rstd = rsqrtf(var + 1e-3f);
#pragma unroll
  for (int cc = 0; cc < 2; ++cc) {
    float o[8];
#pragma unroll
    for (int jj = 0; jj < 8; ++jj) {
      const int idx = i0 + cc * 8 + jj;
      o[jj] = (tv[cc * 8 + jj] - mean) * rstd * gamma[idx] + beta[idx];
      out[base + idx] = o[jj];
    }
    if (imgNH) {
      const int idx8 = i0 + cc * 8;
      uint4 v;
      v.x = pkbf(o[0], o[1]);
      v.y = pkbf(o[2], o[3]);
      v.z = pkbf(o[4], o[5]);
      v.w = pkbf(o[6], o[7]);
      *(uint4*)(&imgNH[((size_t)(row >> 7) * 64 + (idx8 >> 6)) * 8192 +
                       (size_t)((((idx8 >> 3) & 7) * 128) + (row & 127)) * 8]) = v;
    }
  }
}

// Final LN (fast paths): sum 4 fp32 K-split partials + bias, LN, write out.
__launch_bounds__(256)
__global__ void ln_o_k(const float* __restrict__ part, const float* __restrict__ bias,
                       const float* __restrict__ gamma, const float* __restrict__ beta,
                       float* __restrict__ out) {
  const int row = blockIdx.x, t = threadIdx.x;
  const size_t base = (size_t)row * D_DIM;
  const int i0 = t * 4;
  constexpr size_t PSTRIDE = (size_t)1024 * 1024;
  float tv[4];
  float s = 0.f, s2 = 0.f;
#pragma unroll
  for (int j = 0; j < 4; ++j) {
    const size_t idx = base + i0 + j;
    const float x = part[idx] + part[idx + PSTRIDE] + part[idx + 2 * PSTRIDE] +
                    part[idx + 3 * PSTRIDE] + bias[i0 + j];
    tv[j] = x; s += x; s2 += x * x;
  }
#pragma unroll
  for (int off = 32; off; off >>= 1) {
    s += __shfl_down(s, off);
    s2 += __shfl_down(s2, off);
  }
  __shared__ float red[8];
  const int w = t >> 6, lane = t & 63;
  if (lane == 0) { red[w] = s; red[4 + w] = s2; }
  __syncthreads();
  const float S = red[0] + red[1] + red[2] + red[3];
  const float S2 = red[4] + red[5] + red[6] + red[7];
  const float mean = S * (1.f / (float)D_DIM);
  const float var = fmaxf(S2 * (1.f / (float)D_DIM) - mean * mean, 0.f);
  const float rstd = rsqrtf(var + 1e-3f);
#pragma unroll
  for (int j = 0; j < 4; ++j) {
    const int idx = i0 + j;
    out[base + idx] = (tv[j] - mean) * rstd * gamma[idx] + beta[idx];
  }
}

// Legacy final LN: in-place.
__launch_bounds__(256)
__global__ void ln_o_fb(float* io, const float* __restrict__ gamma,
                        const float* __restrict__ beta) {
  const int row = blockIdx.x, t = threadIdx.x;
  const size_t base = (size_t)row * D_DIM;
  const int i0 = t * 4;
  float tv[4];
  float s = 0.f, s2 = 0.f;
#pragma unroll
  for (int j = 0; j < 4; ++j) {
    const float x = io[base + i0 + j];
    tv[j] = x; s += x; s2 += x * x;
  }
#pragma unroll
  for (int off = 32; off; off >>= 1) {
    s += __shfl_down(s, off);
    s2 += __shfl_down(s2, off);
  }
  __shared__ float red[8];
  const int w = t >> 6, lane = t & 63;
  if (lane == 0) { red[w] = s; red[4 + w] = s2; }
  __syncthreads();
  const float S = red[0] + red[1] + red[2] + red[3];
  const float S2 = red[4] + red[5] + red[6] + red[7];
  const float mean = S * (1.f / (float)D_DIM);
  const float var = fmaxf(S2 * (1.f / (float)D_DIM) - mean * mean, 0.f);
  const float rstd = rsqrtf(var + 1e-3f);
#pragma unroll
  for (int j = 0; j < 4; ++j) {
    const int idx = i0 + j;
    io[base + idx] = (tv[j] - mean) * rstd * gamma[idx] + beta[idx];
  }
}

extern "C" void kernel_launch(void* const* d_in, const int* in_sizes, int n_in,
                              void* d_out, int out_size, void* d_ws, size_t ws_size,
                              hipStream_t stream) {
  (void)in_sizes; (void)n_in; (void)out_size;
  const float* x       = (const float*)d_in[0];
  const float* h       = (const float*)d_in[1];
  const float* W_u     = (const float*)d_in[2];
  const float* b_u     = (const float*)d_in[3];
  const float* W_r     = (const float*)d_in[4];
  const float* b_r     = (const float*)d_in[5];
  const float* W_g     = (const float*)d_in[6];
  const float* b_g     = (const float*)d_in[7];
  const float* W_up    = (const float*)d_in[8];
  const float* b_up    = (const float*)d_in[9];
  const float* W_d     = (const float*)d_in[10];
  const float* b_d     = (const float*)d_in[11];
  const float* gamma_h = (const float*)d_in[12];
  const float* beta_h  = (const float*)d_in[13];
  const float* gamma_o = (const float*)d_in[14];
  const float* beta_o  = (const float*)d_in[15];

  float* out_final = (float*)d_out;                              // [B,D] fp32
  float* out_newh  = (float*)d_out + (size_t)B_ROWS * D_DIM;     // [B,H] fp32
  float* u_buf = out_newh;   // u gate fp32 parked in d_out newh region
  float* o_pre = out_final;  // legacy: GEMM3 pre-act fp32 in d_out region

  dim3 blk(256);

  const size_t MiB = 1024 * 1024;
  const size_t SZ_W  = 80 * MiB;   // one weight-image set ([Wu|Wr] or [Wg|Wup])
  const size_t SZ_X  = 2 * MiB;
  const size_t SZ_H  = 8 * MiB;    // also reused as imgNH
  const size_t SZ_RH = 8 * MiB;
  const size_t SZ_G  = 8 * MiB;
  const size_t SZ_UP = 8 * MiB;
  const size_t NEED_SEQ   = SZ_W + SZ_X + SZ_H + SZ_RH + SZ_G + SZ_UP;         // 114 MiB
  const size_t NEED_FUSED = 2 * SZ_W + SZ_X + SZ_H + SZ_RH + SZ_G + SZ_UP;     // 194 MiB

  if (ws_size >= NEED_FUSED) {
    char* ws = (char*)d_ws;
    u16* imgWA = (u16*)(ws);
    u16* imgWB = (u16*)(ws + SZ_W);
    u16* imgX  = (u16*)(ws + 2 * SZ_W);
    u16* imgH  = (u16*)(ws + 2 * SZ_W + SZ_X);
    u16* imgNH = imgH;
    u16* imgRH = (u16*)(ws + 2 * SZ_W + SZ_X + SZ_H);
    u16* ws_g  = (u16*)(ws + 2 * SZ_W + SZ_X + SZ_H + SZ_RH);
    u16* ws_up = (u16*)(ws + 2 * SZ_W + SZ_X + SZ_H + SZ_RH + SZ_G);
    float* part = (float*)ws_g;   // gemm3 partials reuse ws_g+ws_up (dead after ln_h)

    conv_xh_k<<<dim3(80, 8), blk, 0, stream>>>(x, h, imgX, imgH);
    conv_w_k<<<dim3(64, 80), blk, 0, stream>>>(W_u, W_r, imgWA, 4096, 80, 32);
    // gemm1 (512 blocks) + conv of [Wg|Wup] -> imgWB (5120 blocks)
    gemm_conv<1><<<dim3(512 + 5120), blk, 0, stream>>>(
        imgX, imgH, imgWA, b_u, b_r, h, u_buf, imgRH, nullptr, 512,
        W_g, W_up, imgWB, 4096, 80, 32, 6);
    // gemm2 (512 blocks) + conv of W_d -> imgWA (512 blocks, imgWA dead)
    gemm_conv<2><<<dim3(512 + 512), blk, 0, stream>>>(
        imgX, imgRH, imgWB, b_g, b_up, nullptr, nullptr, ws_g, ws_up, 512,
        W_d, nullptr, imgWA, 1024, 64, 8, 3);
    ln_h_k<<<dim3(B_ROWS), blk, 0, stream>>>(u_buf, ws_g, ws_up, h, gamma_h, beta_h,
                                             out_newh, imgNH);
    gemm_img<3><<<dim3(8, 8, 4), blk, 0, stream>>>(imgNH, imgNH, imgWA, nullptr, nullptr,
                                                   nullptr, part, nullptr, nullptr);
    ln_o_k<<<dim3(B_ROWS), blk, 0, stream>>>(part, b_d, gamma_o, beta_o, out_final);
  } else if (ws_size >= NEED_SEQ) {
    char* ws = (char*)d_ws;
    u16* imgW  = (u16*)(ws);
    u16* imgX  = (u16*)(ws + SZ_W);
    u16* imgH  = (u16*)(ws + SZ_W + SZ_X);
    u16* imgNH = imgH;
    u16* imgRH = (u16*)(ws + SZ_W + SZ_X + SZ_H);
    u16* ws_g  = (u16*)(ws + SZ_W + SZ_X + SZ_H + SZ_RH);
    u16* ws_up = (u16*)(ws + SZ_W + SZ_X + SZ_H + SZ_RH + SZ_G);
    float* part = (float*)ws_g;

    conv_xh_k<<<dim3(80, 8), blk, 0, stream>>>(x, h, imgX, imgH);
    conv_w_k<<<dim3(64, 80), blk, 0, stream>>>(W_u, W_r, imgW, 4096, 80, 32);
    gemm_img<1><<<dim3(64, 8), blk, 0, stream>>>(imgX, imgH, imgW, b_u, b_r, h,
                                                 u_buf, imgRH, nullptr);
    conv_w_k<<<dim3(64, 80), blk, 0, stream>>>(W_g, W_up, imgW, 4096, 80, 32);
    gemm_img<2><<<dim3(64, 8), blk, 0, stream>>>(imgX, imgRH, imgW, b_g, b_up, nullptr,
                                                 nullptr, ws_g, ws_up);
    ln_h_k<<<dim3(B_ROWS), blk, 0, stream>>>(u_buf, ws_g, ws_up, h, gamma_h, beta_h,
                                             out_newh, imgNH);
    conv_w_k<<<dim3(8, 64), blk, 0, stream>>>(W_d, nullptr, imgW, 1024, 64, 8);
    gemm_img<3><<<dim3(8, 8, 4), blk, 0, stream>>>(imgNH, imgNH, imgW, nullptr, nullptr,
                                                   nullptr, part, nullptr, nullptr);
    ln_o_k<<<dim3(B_ROWS), blk, 0, stream>>>(part, b_d, gamma_o, beta_o, out_final);
  } else {
    // legacy fallback (24 MB workspace)
    char* ws = (char*)d_ws;
    u16* ws_rh = (u16*)(ws);
    u16* ws_g  = (u16*)(ws + (size_t)8 * MiB);
    u16* ws_up = (u16*)(ws + (size_t)16 * MiB);

    gemm_k<1><<<dim3(64, 8), blk, 0, stream>>>(x, h, nullptr, W_u, W_r, b_u, b_r, h,
                                               u_buf, ws_rh, nullptr);
    gemm_k<2><<<dim3(64, 8), blk, 0, stream>>>(x, nullptr, ws_rh, W_g, W_up, b_g, b_up,
                                               nullptr, nullptr, ws_g, ws_up);
    ln_h_k<<<dim3(B_ROWS), blk, 0, stream>>>(u_buf, ws_g, ws_up, h, gamma_h, beta_h,
                                             out_newh, nullptr);
    gemm_k<3><<<dim3(8, 8), blk, 0, stream>>>(out_newh, nullptr, nullptr, W_d, nullptr,
                                              b_d, nullptr, nullptr, o_pre, nullptr, nullptr);
    ln_o_fb<<<dim3(B_ROWS), blk, 0, stream>>>(o_pre, gamma_o, beta_o);
  }
}